// Round 1
// baseline (65.134 us; speedup 1.0000x reference)
//
#include <hip/hip_runtime.h>
#include <hip/hip_bf16.h>
#include <stdint.h>

// Problem constants
#define B_  8
#define C_  128
#define N_  8192
#define K_  16
#define O_  128
#define TP  128     // points per block in main kernel
#define LDW 136     // padded LDS row stride in bf16 elems (128 + 8)

typedef __attribute__((ext_vector_type(8))) short short8;
typedef __attribute__((ext_vector_type(4))) float f32x4;

__device__ __forceinline__ unsigned short f2bf(float f) {
    union { float f; uint32_t u; } v; v.f = f;
    uint32_t u = v.u;
    return (unsigned short)((u + 0x7FFFu + ((u >> 16) & 1u)) >> 16);  // RNE
}
__device__ __forceinline__ float bflo(uint32_t u) {
    union { uint32_t u; float f; } v; v.u = u << 16; return v.f;
}
__device__ __forceinline__ float bfhi(uint32_t u) {
    union { uint32_t u; float f; } v; v.u = u & 0xFFFF0000u; return v.f;
}
__device__ __forceinline__ void maxin(float m[8], uint4 d) {
    m[0] = fmaxf(m[0], bflo(d.x)); m[1] = fmaxf(m[1], bfhi(d.x));
    m[2] = fmaxf(m[2], bflo(d.y)); m[3] = fmaxf(m[3], bfhi(d.y));
    m[4] = fmaxf(m[4], bflo(d.z)); m[5] = fmaxf(m[5], bfhi(d.z));
    m[6] = fmaxf(m[6], bflo(d.w)); m[7] = fmaxf(m[7], bfhi(d.w));
}

// Kernel 1: x (B, C, N) f32  ->  xt (B*N, C) bf16 row-major.
// Reads coalesced along N; writes 16B/lane at 256B stride (L2 merges lines,
// each block owns whole cachelines of its output region).
__global__ __launch_bounds__(256) void k_transpose(const float* __restrict__ x,
                                                   unsigned short* __restrict__ xt) {
    int blk  = blockIdx.x;        // 8 b * 32 nt * 2 half = 512
    int half = blk & 1;           // c-half: 0 -> c 0..63, 1 -> c 64..127
    int nt   = (blk >> 1) & 31;
    int b    = blk >> 6;
    int n    = nt * 256 + threadIdx.x;
    const float* xb = x + ((size_t)b * C_ + (size_t)half * 64) * N_ + n;
    unsigned short* orow = xt + ((size_t)(b * N_ + n)) * C_ + half * 64;
    #pragma unroll
    for (int cg = 0; cg < 8; ++cg) {
        float v[8];
        #pragma unroll
        for (int j = 0; j < 8; ++j) v[j] = xb[(size_t)(cg * 8 + j) * N_];
        uint32_t pk[4];
        #pragma unroll
        for (int j = 0; j < 4; ++j)
            pk[j] = (uint32_t)f2bf(v[2 * j]) | ((uint32_t)f2bf(v[2 * j + 1]) << 16);
        *(uint4*)(orow + cg * 8) = make_uint4(pk[0], pk[1], pk[2], pk[3]);
    }
}

// Kernel 2: per block: 128 points (one b, contiguous n).
// Phase A: stage idx (2048 ints), W as bf16 (padded rows), bias.
// Phase B: gather 16 neighbor rows/point from xt (contiguous 256B rows),
//          max-reduce (in-lane over 4 k + shfl_xor over 4 k-groups), store
//          agg row (bf16) to padded LDS.
// Phase C: MFMA GEMM 128(out) x 128(pts) x 128(C), bias + ReLU, coalesced store.
__global__ __launch_bounds__(256) void k_main(const unsigned short* __restrict__ xt,
                                              const int* __restrict__ idx,
                                              const float* __restrict__ Wp,
                                              const float* __restrict__ bp,
                                              float* __restrict__ out) {
    __shared__ __align__(16) unsigned short agg[TP * LDW];  // 34816 B
    __shared__ __align__(16) unsigned short wl[O_ * LDW];   // 34816 B
    __shared__ int   idxs[TP * K_];                         // 8192 B
    __shared__ float bl[O_];                                // 512 B

    int t    = threadIdx.x;
    int lane = t & 63;
    int wv   = t >> 6;
    int blk  = blockIdx.x;        // 8 b * 64 ntiles = 512
    int b    = blk >> 6;
    int n0   = (blk & 63) * TP;
    size_t pbase = (size_t)b * N_ + n0;

    // ---- Phase A: staging ----
    const int* ip = idx + pbase * K_;
    #pragma unroll
    for (int i = 0; i < (TP * K_) / 256; ++i)       // 8 iters
        idxs[t + i * 256] = ip[t + i * 256];

    #pragma unroll
    for (int i = 0; i < (O_ * C_ / 4) / 256; ++i) { // 16 iters of float4
        int e = t + i * 256;
        float4 w4 = ((const float4*)Wp)[e];
        int o = e >> 5;            // 32 float4 per row of 128
        int c = (e & 31) * 4;
        uint32_t u0 = (uint32_t)f2bf(w4.x) | ((uint32_t)f2bf(w4.y) << 16);
        uint32_t u1 = (uint32_t)f2bf(w4.z) | ((uint32_t)f2bf(w4.w) << 16);
        *(uint2*)&wl[o * LDW + c] = make_uint2(u0, u1);
    }
    if (t < O_) bl[t] = bp[t];
    __syncthreads();

    // ---- Phase B: gather + max ----
    int cch = lane & 15;   // which 16B chunk of the 256B row
    int kq  = lane >> 4;   // k-quarter 0..3
    for (int i = wv * (TP / 4); i < (wv + 1) * (TP / 4); ++i) {
        int q0 = idxs[i * K_ + kq];
        int q1 = idxs[i * K_ + kq + 4];
        int q2 = idxs[i * K_ + kq + 8];
        int q3 = idxs[i * K_ + kq + 12];
        uint4 d0 = *(const uint4*)(xt + (size_t)q0 * C_ + cch * 8);
        uint4 d1 = *(const uint4*)(xt + (size_t)q1 * C_ + cch * 8);
        uint4 d2 = *(const uint4*)(xt + (size_t)q2 * C_ + cch * 8);
        uint4 d3 = *(const uint4*)(xt + (size_t)q3 * C_ + cch * 8);
        float m[8];
        m[0] = bflo(d0.x); m[1] = bfhi(d0.x);
        m[2] = bflo(d0.y); m[3] = bfhi(d0.y);
        m[4] = bflo(d0.z); m[5] = bfhi(d0.z);
        m[6] = bflo(d0.w); m[7] = bfhi(d0.w);
        maxin(m, d1); maxin(m, d2); maxin(m, d3);
        #pragma unroll
        for (int e = 0; e < 8; ++e) m[e] = fmaxf(m[e], __shfl_xor(m[e], 16));
        #pragma unroll
        for (int e = 0; e < 8; ++e) m[e] = fmaxf(m[e], __shfl_xor(m[e], 32));
        if (kq == 0) {
            uint32_t pk[4];
            #pragma unroll
            for (int j = 0; j < 4; ++j)
                pk[j] = (uint32_t)f2bf(m[2 * j]) | ((uint32_t)f2bf(m[2 * j + 1]) << 16);
            *(uint4*)&agg[i * LDW + cch * 8] = make_uint4(pk[0], pk[1], pk[2], pk[3]);
        }
    }
    __syncthreads();

    // ---- Phase C: MFMA GEMM (16x16x32 bf16) ----
    // Wave wv computes out strip: all 128 o x 32 points (p0..p0+31).
    int p0  = wv * 32;
    int r16 = lane & 15;
    int h   = lane >> 4;   // 0..3

    short8 bfr[2][4];
    #pragma unroll
    for (int pt = 0; pt < 2; ++pt)
        #pragma unroll
        for (int kk = 0; kk < 4; ++kk)
            bfr[pt][kk] = *(const short8*)&agg[(p0 + pt * 16 + r16) * LDW + kk * 32 + h * 8];

    const size_t ob = (size_t)b * O_ * N_ + n0;
    for (int ot = 0; ot < 8; ++ot) {
        short8 af[4];
        #pragma unroll
        for (int kk = 0; kk < 4; ++kk)
            af[kk] = *(const short8*)&wl[(ot * 16 + r16) * LDW + kk * 32 + h * 8];
        #pragma unroll
        for (int pt = 0; pt < 2; ++pt) {
            f32x4 acc = {0.f, 0.f, 0.f, 0.f};
            #pragma unroll
            for (int kk = 0; kk < 4; ++kk)
                acc = __builtin_amdgcn_mfma_f32_16x16x32_bf16(af[kk], bfr[pt][kk], acc, 0, 0, 0);
            // C/D layout (m89): col = lane&15, row = (lane>>4)*4 + reg
            int orow = ot * 16 + h * 4;
            int p    = p0 + pt * 16 + r16;
            float* op = out + ob + (size_t)orow * N_ + p;
            #pragma unroll
            for (int r = 0; r < 4; ++r) {
                float v = acc[r] + bl[orow + r];
                op[(size_t)r * N_] = fmaxf(v, 0.0f);
            }
        }
    }
}

extern "C" void kernel_launch(void* const* d_in, const int* in_sizes, int n_in,
                              void* d_out, int out_size, void* d_ws, size_t ws_size,
                              hipStream_t stream) {
    const float* x    = (const float*)d_in[0];
    const int*   idx  = (const int*)d_in[1];
    const float* W    = (const float*)d_in[2];
    const float* bias = (const float*)d_in[3];
    float* out = (float*)d_out;
    unsigned short* xt = (unsigned short*)d_ws;   // 65536 x 128 bf16 = 16 MB

    hipLaunchKernelGGL(k_transpose, dim3(512), dim3(256), 0, stream, x, xt);
    hipLaunchKernelGGL(k_main,      dim3(512), dim3(256), 0, stream, xt, idx, W, bias, out);
}

// Round 2
// 52.266 us; speedup vs baseline: 1.2462x; 1.2462x over previous
//
#include <hip/hip_runtime.h>
#include <stdint.h>

#define B_  8
#define C_  128
#define N_  8192
#define K_  16
#define O_  128

typedef __attribute__((ext_vector_type(8))) short short8;
typedef __attribute__((ext_vector_type(4))) float f32x4;

__device__ __forceinline__ unsigned short f2bf(float f) {
    union { float f; uint32_t u; } v; v.f = f;
    uint32_t u = v.u;
    return (unsigned short)((u + 0x7FFFu + ((u >> 16) & 1u)) >> 16);  // RNE
}
__device__ __forceinline__ float bflo(uint32_t u) {
    union { uint32_t u; float f; } v; v.u = u << 16; return v.f;
}
__device__ __forceinline__ float bfhi(uint32_t u) {
    union { uint32_t u; float f; } v; v.u = u & 0xFFFF0000u; return v.f;
}
__device__ __forceinline__ void maxin(float m[8], uint4 d) {
    m[0] = fmaxf(m[0], bflo(d.x)); m[1] = fmaxf(m[1], bfhi(d.x));
    m[2] = fmaxf(m[2], bflo(d.y)); m[3] = fmaxf(m[3], bfhi(d.y));
    m[4] = fmaxf(m[4], bflo(d.z)); m[5] = fmaxf(m[5], bfhi(d.z));
    m[6] = fmaxf(m[6], bflo(d.w)); m[7] = fmaxf(m[7], bfhi(d.w));
}

// Kernel 1: x (B, C, N) f32 -> xt (B*N, C) bf16 row-major.
// LDS-staged transpose: coalesced 256B-segment reads along N, conflict-free
// LDS (LDN=65 pad), dense full-row 16B/lane writes (4 complete 256B rows
// per wave-instruction).
__global__ __launch_bounds__(256) void k_transpose(const float* __restrict__ x,
                                                   unsigned short* __restrict__ xt) {
    __shared__ uint32_t lds[64 * 65];   // [c2][n_local], c2 = c/2 packed pair
    int t    = threadIdx.x;
    int lane = t & 63;
    int wv   = t >> 6;
    int blk  = blockIdx.x;            // 8 b * 128 ntiles
    int b    = blk >> 7;
    int n0   = (blk & 127) * 64;

    const float* xb = x + (size_t)b * C_ * N_ + n0 + lane;
    #pragma unroll
    for (int j = 0; j < 16; ++j) {
        int c2 = wv * 16 + j;
        float f0 = xb[(size_t)(2 * c2) * N_];
        float f1 = xb[(size_t)(2 * c2 + 1) * N_];
        lds[c2 * 65 + lane] = (uint32_t)f2bf(f0) | ((uint32_t)f2bf(f1) << 16);
    }
    __syncthreads();

    int rl = lane >> 4;    // row-in-group 0..3
    int ch = lane & 15;    // 16B chunk of the 256B row
    #pragma unroll
    for (int it = 0; it < 4; ++it) {
        int r = it * 16 + wv * 4 + rl;
        uint32_t u0 = lds[(ch * 4 + 0) * 65 + r];
        uint32_t u1 = lds[(ch * 4 + 1) * 65 + r];
        uint32_t u2 = lds[(ch * 4 + 2) * 65 + r];
        uint32_t u3 = lds[(ch * 4 + 3) * 65 + r];
        *(uint4*)(xt + ((size_t)(b * N_ + n0 + r)) * C_ + ch * 8) =
            make_uint4(u0, u1, u2, u3);
    }
}

// Kernel 2: 64 points per block, grid 1024 (4 blocks/CU, 16 waves/CU).
// Gather: lane = (point-in-group, 16B chunk); all K=16 neighbor loads
// independent & in flight per lane; no shuffles, no divergence.
// GEMM: wave owns 32 output rows x 64 points; W fragments f32->bf16 from
// global into registers (no W LDS).
__global__ __launch_bounds__(256, 4) void k_main(const unsigned short* __restrict__ xt,
                                                 const int* __restrict__ idx,
                                                 const float* __restrict__ Wp,
                                                 const float* __restrict__ bp,
                                                 float* __restrict__ out) {
    __shared__ __align__(16) unsigned short agg[64 * 136];  // 17408 B, padded rows
    __shared__ int idxs[64 * K_];                            // 4096 B

    int t    = threadIdx.x;
    int lane = t & 63;
    int wv   = t >> 6;
    int blk  = blockIdx.x;          // 8 b * 128 ntiles
    int b    = blk >> 7;
    int n0   = (blk & 127) * 64;
    size_t pbase = (size_t)b * N_ + n0;

    // ---- stage idx ----
    const int* ip = idx + pbase * K_;
    #pragma unroll
    for (int i = 0; i < 4; ++i) idxs[t + i * 256] = ip[t + i * 256];
    __syncthreads();

    // ---- gather + max: 16 points per wave, 4 points per iteration ----
    int pt  = lane >> 4;   // point within group of 4
    int cch = lane & 15;   // 16B chunk of 256B row
    #pragma unroll
    for (int i = 0; i < 4; ++i) {
        int p = wv * 16 + i * 4 + pt;
        const int* qq = &idxs[p * K_];
        float m[8];
        {
            int q = qq[0];
            uint4 d = *(const uint4*)(xt + (size_t)q * C_ + cch * 8);
            m[0] = bflo(d.x); m[1] = bfhi(d.x);
            m[2] = bflo(d.y); m[3] = bfhi(d.y);
            m[4] = bflo(d.z); m[5] = bfhi(d.z);
            m[6] = bflo(d.w); m[7] = bfhi(d.w);
        }
        #pragma unroll
        for (int k = 1; k < 16; ++k) {
            int q = qq[k];
            uint4 dk = *(const uint4*)(xt + (size_t)q * C_ + cch * 8);
            maxin(m, dk);
        }
        uint32_t pk[4];
        #pragma unroll
        for (int j = 0; j < 4; ++j)
            pk[j] = (uint32_t)f2bf(m[2 * j]) | ((uint32_t)f2bf(m[2 * j + 1]) << 16);
        *(uint4*)&agg[p * 136 + cch * 8] = make_uint4(pk[0], pk[1], pk[2], pk[3]);
    }
    __syncthreads();

    // ---- MFMA GEMM: wave computes o in [wo, wo+32) x all 64 points ----
    int r16 = lane & 15;
    int h   = lane >> 4;
    int wo  = wv * 32;

    short8 af[2][4];
    #pragma unroll
    for (int ot2 = 0; ot2 < 2; ++ot2)
        #pragma unroll
        for (int kk = 0; kk < 4; ++kk) {
            const float* wr = Wp + (size_t)(wo + ot2 * 16 + r16) * C_ + kk * 32 + h * 8;
            float4 a0 = *(const float4*)wr;
            float4 a1 = *(const float4*)(wr + 4);
            short8 s;
            s[0] = (short)f2bf(a0.x); s[1] = (short)f2bf(a0.y);
            s[2] = (short)f2bf(a0.z); s[3] = (short)f2bf(a0.w);
            s[4] = (short)f2bf(a1.x); s[5] = (short)f2bf(a1.y);
            s[6] = (short)f2bf(a1.z); s[7] = (short)f2bf(a1.w);
            af[ot2][kk] = s;
        }
    float4 bb[2];
    bb[0] = *(const float4*)(bp + wo + h * 4);
    bb[1] = *(const float4*)(bp + wo + 16 + h * 4);

    const size_t ob = (size_t)b * O_ * N_ + n0;
    #pragma unroll
    for (int pt4 = 0; pt4 < 4; ++pt4) {
        short8 bfr[4];
        #pragma unroll
        for (int kk = 0; kk < 4; ++kk)
            bfr[kk] = *(const short8*)&agg[(pt4 * 16 + r16) * 136 + kk * 32 + h * 8];
        #pragma unroll
        for (int ot2 = 0; ot2 < 2; ++ot2) {
            f32x4 acc = {0.f, 0.f, 0.f, 0.f};
            #pragma unroll
            for (int kk = 0; kk < 4; ++kk)
                acc = __builtin_amdgcn_mfma_f32_16x16x32_bf16(af[ot2][kk], bfr[kk], acc, 0, 0, 0);
            // C/D layout: col = lane&15 (point), row = (lane>>4)*4 + reg
            int orow = wo + ot2 * 16 + h * 4;
            float* op = out + ob + (size_t)orow * N_ + pt4 * 16 + r16;
            float4 bv = bb[ot2];
            op[0]              = fmaxf(acc[0] + bv.x, 0.f);
            op[(size_t)N_]     = fmaxf(acc[1] + bv.y, 0.f);
            op[(size_t)2 * N_] = fmaxf(acc[2] + bv.z, 0.f);
            op[(size_t)3 * N_] = fmaxf(acc[3] + bv.w, 0.f);
        }
    }
}

extern "C" void kernel_launch(void* const* d_in, const int* in_sizes, int n_in,
                              void* d_out, int out_size, void* d_ws, size_t ws_size,
                              hipStream_t stream) {
    const float* x    = (const float*)d_in[0];
    const int*   idx  = (const int*)d_in[1];
    const float* W    = (const float*)d_in[2];
    const float* bias = (const float*)d_in[3];
    float* out = (float*)d_out;
    unsigned short* xt = (unsigned short*)d_ws;   // 65536 x 128 bf16 = 16 MB

    hipLaunchKernelGGL(k_transpose, dim3(1024), dim3(256), 0, stream, x, xt);
    hipLaunchKernelGGL(k_main,      dim3(1024), dim3(256), 0, stream, xt, idx, W, bias, out);
}